// Round 21
// baseline (1049.973 us; speedup 1.0000x reference)
//
#include <hip/hip_runtime.h>
#include <hip/hip_bf16.h>
#include <math.h>

// build m21 = k20 + fused spectral chains (7 kernels/layer -> 3) + occupancy
// bump on pointwise kernels (min-waves 4).
#define XYZ 135168   // 64*64*33
#define W 20
#define NMODE 2048   // 16*16*8
#define NREAL 3584   // 16*16*14

__device__ __forceinline__ float m21_erf(float x) {
    float s = (x < 0.f) ? -1.f : 1.f;
    float a = fabsf(x);
    float t = 1.f / fmaf(0.3275911f, a, 1.f);
    float poly = t * fmaf(t, fmaf(t, fmaf(t, fmaf(t, 1.061405429f, -1.453152027f),
                                           1.421413741f), -0.284496736f), 0.254829592f);
    float e = __expf(-a * a);
    return s * (1.f - poly * e);
}
__device__ __forceinline__ float m21_gelu(float v) {
    return 0.5f * v * (1.0f + m21_erf(v * 0.7071067811865476f));
}

__global__ __launch_bounds__(256, 4)
void m21_fc0(const float* __restrict__ xr_in, const float* __restrict__ xi_in,
             const float* __restrict__ fr, const float* __restrict__ fi,
             float* __restrict__ xre, float* __restrict__ xim) {
    int idx = blockIdx.x * blockDim.x + threadIdx.x;
    if (idx >= 4 * XYZ) return;
    int b = idx / XYZ, p = idx % XYZ;
    float ar[3], ai[3];
#pragma unroll
    for (int i = 0; i < 3; i++) {
        ar[i] = xr_in[(size_t)(b * 3 + i) * XYZ + p];
        ai[i] = xi_in[(size_t)(b * 3 + i) * XYZ + p];
    }
#pragma unroll
    for (int o = 0; o < W; o++) {
        float rr = 0.f, ii = 0.f;
#pragma unroll
        for (int i = 0; i < 3; i++) {
            float wr = fr[i * W + o], wi = fi[i * W + o];
            rr += ar[i] * wr - ai[i] * wi;
            ii += ar[i] * wi + ai[i] * wr;
        }
        xre[(size_t)(b * W + o) * XYZ + p] = rr;
        xim[(size_t)(b * W + o) * XYZ + p] = ii;
    }
}

// FUSED inverse chain: gather corners -> ifftX -> ifftY -> irfftZ.
// One block per (b,c) slab; whole slab lives in LDS. Layouts identical to the
// verified unfused kernels.
__global__ __launch_bounds__(256, 2)
void m21_spec_inv(const float* __restrict__ xre, const float* __restrict__ xim,
                  float* __restrict__ r1) {
    __shared__ float s0r[2048], s0i[2048], s1r[2048], s1i[2048];
    int bc = blockIdx.x;
    int tid = threadIdx.x;
    const float* pr = xre + (size_t)bc * XYZ;
    const float* pi = xim + (size_t)bc * XYZ;
    // gather: s0[kx*128 + ky*8 + kz]
    for (int t = tid; t < 2048; t += 256) {
        int kz = t & 7, ky = (t >> 3) & 15, kx = t >> 7;
        int row = (kx < 8) ? kx : kx + 48;
        int col = (ky < 8) ? ky : ky + 48;
        int off = (row * 64 + col) * 33 + kz;
        s0r[t] = pr[off];
        s0i[t] = pi[off];
    }
    __syncthreads();
    // ifftX: s1[nx*128+ky*8+kz] = 1/16 sum_kx s0[kx*128+ky*8+kz] e^{+i}
    for (int t = tid; t < 2048; t += 256) {
        int kz = t & 7, ky = (t >> 3) & 15, nx = t >> 7;
        int base = ky * 8 + kz;
        float accr = 0.f, acci = 0.f;
        for (int kx = 0; kx < 16; kx++) {
            float vr = s0r[base + kx * 128], vi = s0i[base + kx * 128];
            int m = (kx * nx) & 15;
            float s, c;
            sincosf((float)m * 0.39269908169872414f, &s, &c);
            accr += vr * c - vi * s;
            acci += vr * s + vi * c;
        }
        s1r[t] = accr * 0.0625f;
        s1i[t] = acci * 0.0625f;
    }
    __syncthreads();
    // ifftY: s0[nx*128+ny*8+kz] = 1/16 sum_ky s1[nx*128+ky*8+kz] e^{+i}
    for (int t = tid; t < 2048; t += 256) {
        int kz = t & 7, ny = (t >> 3) & 15, nx = t >> 7;
        int base = nx * 128 + kz;
        float accr = 0.f, acci = 0.f;
        for (int ky = 0; ky < 16; ky++) {
            float vr = s1r[base + ky * 8], vi = s1i[base + ky * 8];
            int m = (ky * ny) & 15;
            float s, c;
            sincosf((float)m * 0.39269908169872414f, &s, &c);
            accr += vr * c - vi * s;
            acci += vr * s + vi * c;
        }
        s0r[t] = accr * 0.0625f;
        s0i[t] = acci * 0.0625f;
    }
    __syncthreads();
    // irfftZ: r1[bc*3584 + q*14 + nz], src s0[q*8 + k]
    for (int t = tid; t < 3584; t += 256) {
        int nz = t % 14;
        int q = t / 14;
        int base = q * 8;
        float acc = s0r[base];
        float re7 = s0r[base + 7];
        acc += (nz & 1) ? -re7 : re7;
        for (int k = 1; k < 7; k++) {
            int m = (k * nz) % 14;
            float s, c;
            sincosf((float)m * 0.4487989505128276f, &s, &c);
            acc += 2.f * (s0r[base + k] * c - s0i[base + k] * s);
        }
        r1[(size_t)bc * 3584 + t] = acc * (1.0f / 14.0f);
    }
}

__global__ __launch_bounds__(256, 4)
void m21_mix(const float* __restrict__ r1, const float* __restrict__ wconv,
             int l, float* __restrict__ r2) {
    int t = blockIdx.x * blockDim.x + threadIdx.x;
    if (t >= 80 * NREAL) return;
    int p = t % NREAL;
    int o = (t / NREAL) % W;
    int b = t / (NREAL * W);
    const float* wl = wconv + (size_t)l * W * W * NREAL;
    float acc = 0.f;
#pragma unroll
    for (int i = 0; i < W; i++)
        acc += r1[(size_t)(b * W + i) * NREAL + p] * wl[(size_t)(i * W + o) * NREAL + p];
    r2[t] = acc;
}

// FUSED forward chain: rfftZ -> fftX -> fftY. One block per (b,c) slab.
__global__ __launch_bounds__(256, 2)
void m21_spec_fwd(const float* __restrict__ r2,
                  float* __restrict__ are, float* __restrict__ aim) {
    __shared__ float sr[3584];
    __shared__ float c1r[2048], c1i[2048], c2r[2048], c2i[2048];
    int bc = blockIdx.x;
    int tid = threadIdx.x;
    for (int t = tid; t < 3584; t += 256) sr[t] = r2[(size_t)bc * 3584 + t];
    __syncthreads();
    // rfftZ: c1[q*8+k] = sum_n sr[q*14+n] e^{-i 2pi k n/14}
    for (int t = tid; t < 2048; t += 256) {
        int k = t & 7;
        int q = t >> 3;
        int base = q * 14;
        float accr = 0.f, acci = 0.f;
        for (int n = 0; n < 14; n++) {
            float v = sr[base + n];
            int m = (k * n) % 14;
            float s, c;
            sincosf((float)m * 0.4487989505128276f, &s, &c);
            accr += v * c;
            acci -= v * s;
        }
        c1r[t] = accr;
        c1i[t] = acci;
    }
    __syncthreads();
    // fftX: c2[kx*128+ny*8+kz] = sum_nx c1[nx*128+ny*8+kz] e^{-i}
    for (int t = tid; t < 2048; t += 256) {
        int kz = t & 7, ny = (t >> 3) & 15, kx = t >> 7;
        int base = ny * 8 + kz;
        float accr = 0.f, acci = 0.f;
        for (int nx = 0; nx < 16; nx++) {
            float vr = c1r[base + nx * 128], vi = c1i[base + nx * 128];
            int m = (kx * nx) & 15;
            float s, c;
            sincosf((float)m * 0.39269908169872414f, &s, &c);
            accr += vr * c + vi * s;
            acci += vi * c - vr * s;
        }
        c2r[t] = accr;
        c2i[t] = acci;
    }
    __syncthreads();
    // fftY: E[kx*128+ky*8+kz] = sum_ny c2[kx*128+ny*8+kz] e^{-i}
    for (int t = tid; t < 2048; t += 256) {
        int kz = t & 7, ky = (t >> 3) & 15, kx = t >> 7;
        int base = kx * 128 + kz;
        float accr = 0.f, acci = 0.f;
        for (int ny = 0; ny < 16; ny++) {
            float vr = c2r[base + ny * 8], vi = c2i[base + ny * 8];
            int m = (ky * ny) & 15;
            float s, c;
            sincosf((float)m * 0.39269908169872414f, &s, &c);
            accr += vr * c + vi * s;
            acci += vi * c - vr * s;
        }
        are[(size_t)bc * 2048 + t] = accr;
        aim[(size_t)bc * 2048 + t] = acci;
    }
}

__global__ __launch_bounds__(256, 4)
void m21_combine(float* __restrict__ xre, float* __restrict__ xim,
                 const float* __restrict__ ere, const float* __restrict__ eim,
                 const float* __restrict__ wpt_r, const float* __restrict__ wpt_i,
                 int l, const float* __restrict__ smooth, int apply_gelu) {
    __shared__ float wr[W * W], wi[W * W];
    for (int i = threadIdx.x; i < W * W; i += blockDim.x) {
        wr[i] = wpt_r[l * W * W + i];
        wi[i] = wpt_i[l * W * W + i];
    }
    __syncthreads();
    int idx = blockIdx.x * blockDim.x + threadIdx.x;
    if (idx >= 4 * XYZ) return;
    int b = idx / XYZ, p = idx % XYZ;
    int gz = p % 33;
    int gxy = p / 33;
    int gy = gxy & 63;
    int gx = gxy >> 6;
    int kx = (gx < 8) ? gx : ((gx >= 56) ? gx - 48 : -1);
    int ky = (gy < 8) ? gy : ((gy >= 56) ? gy - 48 : -1);
    bool corner = (kx >= 0) && (ky >= 0) && (gz < 8);
    float sm = smooth[p];
    float ar[W], ai[W];
#pragma unroll
    for (int i = 0; i < W; i++) {
        ar[i] = xre[(size_t)(b * W + i) * XYZ + p];
        ai[i] = xim[(size_t)(b * W + i) * XYZ + p];
    }
    int ebase = corner ? (b * W * NMODE + (kx * 16 + ky) * 8 + gz) : 0;
    for (int o = 0; o < W; o++) {
        float rr = 0.f, ii = 0.f;
#pragma unroll
        for (int i = 0; i < W; i++) {
            float wwr = wr[i * W + o], wwi = wi[i * W + o];
            rr += ar[i] * wwr - ai[i] * wwi;
            ii += ar[i] * wwi + ai[i] * wwr;
        }
        if (corner) {
            rr += ere[ebase + o * NMODE];
            ii += eim[ebase + o * NMODE];
        }
        rr *= sm;
        ii *= sm;
        if (apply_gelu) {
            rr = m21_gelu(rr);
            ii = m21_gelu(ii);
        }
        xre[(size_t)(b * W + o) * XYZ + p] = rr;
        xim[(size_t)(b * W + o) * XYZ + p] = ii;
    }
}

__global__ __launch_bounds__(256, 4)
void m21_tail(const float* __restrict__ xre, const float* __restrict__ xim,
              const float* __restrict__ f1r, const float* __restrict__ f1i,
              const float* __restrict__ f2r, const float* __restrict__ f2i,
              float* __restrict__ outf) {
    __shared__ __align__(16) float w1r[W * 128], w1i[W * 128];
    __shared__ __align__(16) float w2r[3 * 128], w2i[3 * 128];
    for (int i = threadIdx.x; i < W * 128; i += blockDim.x) {
        w1r[i] = f1r[i];
        w1i[i] = f1i[i];
    }
    for (int i = threadIdx.x; i < 3 * 128; i += blockDim.x) {
        int j = i & 127, o = i >> 7;
        w2r[o * 128 + j] = f2r[j * 3 + o];
        w2i[o * 128 + j] = f2i[j * 3 + o];
    }
    __syncthreads();
    int idx = blockIdx.x * blockDim.x + threadIdx.x;
    if (idx >= 4 * XYZ) return;
    int b = idx / XYZ, p = idx % XYZ;
    float ar[W], ai[W];
#pragma unroll
    for (int i = 0; i < W; i++) {
        ar[i] = xre[(size_t)(b * W + i) * XYZ + p];
        ai[i] = xim[(size_t)(b * W + i) * XYZ + p];
    }
    float accr[3] = {0.f, 0.f, 0.f};
    for (int jc = 0; jc < 16; jc++) {
        int jb = jc * 8;
        float tr[8], ti[8];
#pragma unroll
        for (int jj = 0; jj < 8; jj++) { tr[jj] = 0.f; ti[jj] = 0.f; }
#pragma unroll 1
        for (int i = 0; i < W; i++) {
            float4 wrA = *(const float4*)&w1r[i * 128 + jb];
            float4 wrB = *(const float4*)&w1r[i * 128 + jb + 4];
            float4 wiA = *(const float4*)&w1i[i * 128 + jb];
            float4 wiB = *(const float4*)&w1i[i * 128 + jb + 4];
            float xr_ = ar[i], xi_ = ai[i];
            tr[0] += xr_ * wrA.x - xi_ * wiA.x;  ti[0] += xr_ * wiA.x + xi_ * wrA.x;
            tr[1] += xr_ * wrA.y - xi_ * wiA.y;  ti[1] += xr_ * wiA.y + xi_ * wrA.y;
            tr[2] += xr_ * wrA.z - xi_ * wiA.z;  ti[2] += xr_ * wiA.z + xi_ * wrA.z;
            tr[3] += xr_ * wrA.w - xi_ * wiA.w;  ti[3] += xr_ * wiA.w + xi_ * wrA.w;
            tr[4] += xr_ * wrB.x - xi_ * wiB.x;  ti[4] += xr_ * wiB.x + xi_ * wrB.x;
            tr[5] += xr_ * wrB.y - xi_ * wiB.y;  ti[5] += xr_ * wiB.y + xi_ * wrB.y;
            tr[6] += xr_ * wrB.z - xi_ * wiB.z;  ti[6] += xr_ * wiB.z + xi_ * wrB.z;
            tr[7] += xr_ * wrB.w - xi_ * wiB.w;  ti[7] += xr_ * wiB.w + xi_ * wrB.w;
        }
#pragma unroll
        for (int jj = 0; jj < 8; jj++) {
            tr[jj] = m21_gelu(tr[jj]);
            ti[jj] = m21_gelu(ti[jj]);
        }
#pragma unroll
        for (int o = 0; o < 3; o++) {
            float4 crA = *(const float4*)&w2r[o * 128 + jb];
            float4 crB = *(const float4*)&w2r[o * 128 + jb + 4];
            float4 ciA = *(const float4*)&w2i[o * 128 + jb];
            float4 ciB = *(const float4*)&w2i[o * 128 + jb + 4];
            accr[o] += tr[0] * crA.x - ti[0] * ciA.x;
            accr[o] += tr[1] * crA.y - ti[1] * ciA.y;
            accr[o] += tr[2] * crA.z - ti[2] * ciA.z;
            accr[o] += tr[3] * crA.w - ti[3] * ciA.w;
            accr[o] += tr[4] * crB.x - ti[4] * ciB.x;
            accr[o] += tr[5] * crB.y - ti[5] * ciB.y;
            accr[o] += tr[6] * crB.z - ti[6] * ciB.z;
            accr[o] += tr[7] * crB.w - ti[7] * ciB.w;
        }
    }
#pragma unroll
    for (int o = 0; o < 3; o++) {
        size_t k = (size_t)(b * 3 + o) * XYZ + p;
        outf[k] = __bfloat162float(__float2bfloat16(accr[o]));
    }
}

extern "C" void kernel_launch(void* const* d_in, const int* in_sizes, int n_in,
                              void* d_out, int out_size, void* d_ws, size_t ws_size,
                              hipStream_t stream) {
    const float* x_r    = (const float*)d_in[0];
    const float* x_i    = (const float*)d_in[1];
    const float* smooth = (const float*)d_in[2];
    const float* wconv  = (const float*)d_in[3];
    const float* wpt_r  = (const float*)d_in[4];
    const float* wpt_i  = (const float*)d_in[5];
    const float* fc0_r  = (const float*)d_in[6];
    const float* fc0_i  = (const float*)d_in[7];
    const float* fc1_r  = (const float*)d_in[8];
    const float* fc1_i  = (const float*)d_in[9];
    const float* fc2_r  = (const float*)d_in[10];
    const float* fc2_i  = (const float*)d_in[11];
    float* outf = (float*)d_out;

    const size_t NBW = (size_t)4 * W * XYZ;
    const size_t NM  = (size_t)80 * NMODE;
    const size_t NR  = (size_t)80 * NREAL;

    float* modebuf = (float*)d_ws;
    float* are = modebuf;
    float* aim = are + NM;
    float* r1  = aim + NM;
    float* r2  = r1 + NR;
    float* xre = r2 + NR;
    float* xim = xre + NBW;

    dim3 blk(256);
    const int gP = (4 * XYZ) / 256;
    const int gR = (80 * NREAL) / 256;

    m21_fc0<<<gP, blk, 0, stream>>>(x_r, x_i, fc0_r, fc0_i, xre, xim);
    for (int l = 0; l < 4; l++) {
        m21_spec_inv<<<80, blk, 0, stream>>>(xre, xim, r1);
        m21_mix<<<gR, blk, 0, stream>>>(r1, wconv, l, r2);
        m21_spec_fwd<<<80, blk, 0, stream>>>(r2, are, aim);
        m21_combine<<<gP, blk, 0, stream>>>(xre, xim, are, aim, wpt_r, wpt_i, l,
                                            smooth, (l < 3) ? 1 : 0);
    }
    m21_tail<<<gP, blk, 0, stream>>>(xre, xim, fc1_r, fc1_i, fc2_r, fc2_i, outf);
}

// Round 22
// 729.101 us; speedup vs baseline: 1.4401x; 1.4401x over previous
//
#include <hip/hip_runtime.h>
#include <hip/hip_bf16.h>
#include <math.h>

// build n22 = k20 (749us) + per-(bc,kz)-plane XY fusion (full-GPU grids, fixes
// m21's 80-block starvation) + combine(l=3) fused into the tail.
#define XYZ 135168   // 64*64*33
#define W 20
#define NMODE 2048   // 16*16*8
#define NREAL 3584   // 16*16*14

__device__ __forceinline__ float n22_erf(float x) {
    float s = (x < 0.f) ? -1.f : 1.f;
    float a = fabsf(x);
    float t = 1.f / fmaf(0.3275911f, a, 1.f);
    float poly = t * fmaf(t, fmaf(t, fmaf(t, fmaf(t, 1.061405429f, -1.453152027f),
                                           1.421413741f), -0.284496736f), 0.254829592f);
    float e = __expf(-a * a);
    return s * (1.f - poly * e);
}
__device__ __forceinline__ float n22_gelu(float v) {
    return 0.5f * v * (1.0f + n22_erf(v * 0.7071067811865476f));
}

__global__ __launch_bounds__(256, 4)
void n22_fc0(const float* __restrict__ xr_in, const float* __restrict__ xi_in,
             const float* __restrict__ fr, const float* __restrict__ fi,
             float* __restrict__ xre, float* __restrict__ xim) {
    int idx = blockIdx.x * blockDim.x + threadIdx.x;
    if (idx >= 4 * XYZ) return;
    int b = idx / XYZ, p = idx % XYZ;
    float ar[3], ai[3];
#pragma unroll
    for (int i = 0; i < 3; i++) {
        ar[i] = xr_in[(size_t)(b * 3 + i) * XYZ + p];
        ai[i] = xi_in[(size_t)(b * 3 + i) * XYZ + p];
    }
#pragma unroll
    for (int o = 0; o < W; o++) {
        float rr = 0.f, ii = 0.f;
#pragma unroll
        for (int i = 0; i < 3; i++) {
            float wr = fr[i * W + o], wi = fi[i * W + o];
            rr += ar[i] * wr - ai[i] * wi;
            ii += ar[i] * wi + ai[i] * wr;
        }
        xre[(size_t)(b * W + o) * XYZ + p] = rr;
        xim[(size_t)(b * W + o) * XYZ + p] = ii;
    }
}

// FUSED gather + ifftX + ifftY for one (bc, kz) plane. 640 blocks, 1 elem/thread.
// out: a[bc*2048 + (nx*16+ny)*8 + kz]
__global__ __launch_bounds__(256, 4)
void n22_ixy(const float* __restrict__ xre, const float* __restrict__ xim,
             float* __restrict__ aRe, float* __restrict__ aIm) {
    __shared__ float s0r[256], s0i[256], s1r[256], s1i[256];
    int bc = blockIdx.x >> 3;
    int kz = blockIdx.x & 7;
    int t = threadIdx.x;          // kx*16+ky view
    int hi = t >> 4, lo = t & 15; // hi=kx, lo=ky (stage 1)
    {
        int row = (hi < 8) ? hi : hi + 48;
        int col = (lo < 8) ? lo : lo + 48;
        int off = (row * 64 + col) * 33 + kz;
        s0r[t] = xre[(size_t)bc * XYZ + off];
        s0i[t] = xim[(size_t)bc * XYZ + off];
    }
    __syncthreads();
    // ifftX: s1[nx*16+ky] = 1/16 sum_kx s0[kx*16+ky] e^{+2pi i kx nx/16}
    {
        int nx = hi, ky = lo;
        float accr = 0.f, acci = 0.f;
        for (int kx = 0; kx < 16; kx++) {
            float vr = s0r[kx * 16 + ky], vi = s0i[kx * 16 + ky];
            int m = (kx * nx) & 15;
            float s, c;
            sincosf((float)m * 0.39269908169872414f, &s, &c);
            accr += vr * c - vi * s;
            acci += vr * s + vi * c;
        }
        s1r[t] = accr * 0.0625f;
        s1i[t] = acci * 0.0625f;
    }
    __syncthreads();
    // ifftY: out[nx*16+ny] = 1/16 sum_ky s1[nx*16+ky] e^{+2pi i ky ny/16}
    {
        int nx = hi, ny = lo;
        float accr = 0.f, acci = 0.f;
        for (int ky = 0; ky < 16; ky++) {
            float vr = s1r[nx * 16 + ky], vi = s1i[nx * 16 + ky];
            int m = (ky * ny) & 15;
            float s, c;
            sincosf((float)m * 0.39269908169872414f, &s, &c);
            accr += vr * c - vi * s;
            acci += vr * s + vi * c;
        }
        size_t o = (size_t)bc * 2048 + (size_t)t * 8 + kz;
        aRe[o] = accr * 0.0625f;
        aIm[o] = acci * 0.0625f;
    }
}

// irfftZ: r1[qg*14+nz] from a[qg*8+k]  (qg = bc*256 + nx*16+ny, global)
__global__ __launch_bounds__(256, 4)
void n22_irfftz(const float* __restrict__ aRe, const float* __restrict__ aIm,
                float* __restrict__ r1) {
    int t = blockIdx.x * blockDim.x + threadIdx.x;
    if (t >= 80 * NREAL) return;
    int nz = t % 14;
    int q = t / 14;
    int base = q * 8;
    float acc = aRe[base];
    float re7 = aRe[base + 7];
    acc += (nz & 1) ? -re7 : re7;
    for (int k = 1; k < 7; k++) {
        int m = (k * nz) % 14;
        float s, c;
        sincosf((float)m * 0.4487989505128276f, &s, &c);
        acc += 2.f * (aRe[base + k] * c - aIm[base + k] * s);
    }
    r1[t] = acc * (1.0f / 14.0f);
}

__global__ __launch_bounds__(256, 4)
void n22_mix(const float* __restrict__ r1, const float* __restrict__ wconv,
             int l, float* __restrict__ r2) {
    int t = blockIdx.x * blockDim.x + threadIdx.x;
    if (t >= 80 * NREAL) return;
    int p = t % NREAL;
    int o = (t / NREAL) % W;
    int b = t / (NREAL * W);
    const float* wl = wconv + (size_t)l * W * W * NREAL;
    float acc = 0.f;
#pragma unroll
    for (int i = 0; i < W; i++)
        acc += r1[(size_t)(b * W + i) * NREAL + p] * wl[(size_t)(i * W + o) * NREAL + p];
    r2[t] = acc;
}

// rfftZ: c1[qg*8+k] = sum_n r2[qg*14+n] e^{-2pi i k n/14}
__global__ __launch_bounds__(256, 4)
void n22_rfftz(const float* __restrict__ r2,
               float* __restrict__ c1Re, float* __restrict__ c1Im) {
    int t = blockIdx.x * blockDim.x + threadIdx.x;
    if (t >= 80 * NMODE) return;
    int k = t & 7;
    int q = t >> 3;
    int base = q * 14;
    float accr = 0.f, acci = 0.f;
    for (int n = 0; n < 14; n++) {
        float v = r2[base + n];
        int m = (k * n) % 14;
        float s, c;
        sincosf((float)m * 0.4487989505128276f, &s, &c);
        accr += v * c;
        acci -= v * s;
    }
    c1Re[t] = accr;
    c1Im[t] = acci;
}

// FUSED fftX + fftY for one (bc, kz) plane. 640 blocks.
// in:  c1[bc*2048 + (nx*16+ny)*8 + kz]
// out: E[bc*2048 + (kx*16+ky)*8 + kz]
__global__ __launch_bounds__(256, 4)
void n22_fxy(const float* __restrict__ c1Re, const float* __restrict__ c1Im,
             float* __restrict__ eRe, float* __restrict__ eIm) {
    __shared__ float s0r[256], s0i[256], s1r[256], s1i[256];
    int bc = blockIdx.x >> 3;
    int kz = blockIdx.x & 7;
    int t = threadIdx.x;
    int hi = t >> 4, lo = t & 15;
    {
        size_t o = (size_t)bc * 2048 + (size_t)t * 8 + kz;
        s0r[t] = c1Re[o];   // s0[nx*16+ny]
        s0i[t] = c1Im[o];
    }
    __syncthreads();
    // fftX: s1[kx*16+ny] = sum_nx s0[nx*16+ny] e^{-2pi i kx nx/16}
    {
        int kx = hi, ny = lo;
        float accr = 0.f, acci = 0.f;
        for (int nx = 0; nx < 16; nx++) {
            float vr = s0r[nx * 16 + ny], vi = s0i[nx * 16 + ny];
            int m = (kx * nx) & 15;
            float s, c;
            sincosf((float)m * 0.39269908169872414f, &s, &c);
            accr += vr * c + vi * s;
            acci += vi * c - vr * s;
        }
        s1r[t] = accr;
        s1i[t] = acci;
    }
    __syncthreads();
    // fftY: E[kx*16+ky] = sum_ny s1[kx*16+ny] e^{-2pi i ky ny/16}
    {
        int kx = hi, ky = lo;
        float accr = 0.f, acci = 0.f;
        for (int ny = 0; ny < 16; ny++) {
            float vr = s1r[kx * 16 + ny], vi = s1i[kx * 16 + ny];
            int m = (ky * ny) & 15;
            float s, c;
            sincosf((float)m * 0.39269908169872414f, &s, &c);
            accr += vr * c + vi * s;
            acci += vi * c - vr * s;
        }
        size_t o = (size_t)bc * 2048 + (size_t)t * 8 + kz;
        eRe[o] = accr;
        eIm[o] = acci;
    }
}

__global__ __launch_bounds__(256, 4)
void n22_combine(float* __restrict__ xre, float* __restrict__ xim,
                 const float* __restrict__ ere, const float* __restrict__ eim,
                 const float* __restrict__ wpt_r, const float* __restrict__ wpt_i,
                 int l, const float* __restrict__ smooth) {
    __shared__ float wr[W * W], wi[W * W];
    for (int i = threadIdx.x; i < W * W; i += blockDim.x) {
        wr[i] = wpt_r[l * W * W + i];
        wi[i] = wpt_i[l * W * W + i];
    }
    __syncthreads();
    int idx = blockIdx.x * blockDim.x + threadIdx.x;
    if (idx >= 4 * XYZ) return;
    int b = idx / XYZ, p = idx % XYZ;
    int gz = p % 33;
    int gxy = p / 33;
    int gy = gxy & 63;
    int gx = gxy >> 6;
    int kx = (gx < 8) ? gx : ((gx >= 56) ? gx - 48 : -1);
    int ky = (gy < 8) ? gy : ((gy >= 56) ? gy - 48 : -1);
    bool corner = (kx >= 0) && (ky >= 0) && (gz < 8);
    float sm = smooth[p];
    float ar[W], ai[W];
#pragma unroll
    for (int i = 0; i < W; i++) {
        ar[i] = xre[(size_t)(b * W + i) * XYZ + p];
        ai[i] = xim[(size_t)(b * W + i) * XYZ + p];
    }
    int ebase = corner ? (b * W * NMODE + (kx * 16 + ky) * 8 + gz) : 0;
    for (int o = 0; o < W; o++) {
        float rr = 0.f, ii = 0.f;
#pragma unroll
        for (int i = 0; i < W; i++) {
            float wwr = wr[i * W + o], wwi = wi[i * W + o];
            rr += ar[i] * wwr - ai[i] * wwi;
            ii += ar[i] * wwi + ai[i] * wwr;
        }
        if (corner) {
            rr += ere[ebase + o * NMODE];
            ii += eim[ebase + o * NMODE];
        }
        rr *= sm;
        ii *= sm;
        rr = n22_gelu(rr);   // layers 0..2 always gelu
        ii = n22_gelu(ii);
        xre[(size_t)(b * W + o) * XYZ + p] = rr;
        xim[(size_t)(b * W + o) * XYZ + p] = ii;
    }
}

// TAIL with combine(l=3) fused in (no gelu on l=3), then fc1 -> cgelu -> fc2.
__global__ __launch_bounds__(256, 2)
void n22_tail(const float* __restrict__ xre, const float* __restrict__ xim,
              const float* __restrict__ ere, const float* __restrict__ eim,
              const float* __restrict__ wpt_r, const float* __restrict__ wpt_i,
              const float* __restrict__ smooth,
              const float* __restrict__ f1r, const float* __restrict__ f1i,
              const float* __restrict__ f2r, const float* __restrict__ f2i,
              float* __restrict__ outf) {
    __shared__ __align__(16) float w1r[W * 128], w1i[W * 128];
    __shared__ __align__(16) float w2r[3 * 128], w2i[3 * 128];
    __shared__ float pwr[W * W], pwi[W * W];
    for (int i = threadIdx.x; i < W * 128; i += blockDim.x) {
        w1r[i] = f1r[i];
        w1i[i] = f1i[i];
    }
    for (int i = threadIdx.x; i < 3 * 128; i += blockDim.x) {
        int j = i & 127, o = i >> 7;
        w2r[o * 128 + j] = f2r[j * 3 + o];
        w2i[o * 128 + j] = f2i[j * 3 + o];
    }
    for (int i = threadIdx.x; i < W * W; i += blockDim.x) {
        pwr[i] = wpt_r[3 * W * W + i];
        pwi[i] = wpt_i[3 * W * W + i];
    }
    __syncthreads();
    int idx = blockIdx.x * blockDim.x + threadIdx.x;
    if (idx >= 4 * XYZ) return;
    int b = idx / XYZ, p = idx % XYZ;
    // ---- fused combine l=3 (no gelu) ----
    int gz = p % 33;
    int gxy = p / 33;
    int gy = gxy & 63;
    int gx = gxy >> 6;
    int kxc = (gx < 8) ? gx : ((gx >= 56) ? gx - 48 : -1);
    int kyc = (gy < 8) ? gy : ((gy >= 56) ? gy - 48 : -1);
    bool corner = (kxc >= 0) && (kyc >= 0) && (gz < 8);
    float sm = smooth[p];
    float rr_[W], ri_[W];
    {
        float ar[W], ai[W];
#pragma unroll
        for (int i = 0; i < W; i++) {
            ar[i] = xre[(size_t)(b * W + i) * XYZ + p];
            ai[i] = xim[(size_t)(b * W + i) * XYZ + p];
        }
        int ebase = corner ? (b * W * NMODE + (kxc * 16 + kyc) * 8 + gz) : 0;
#pragma unroll 1
        for (int o = 0; o < W; o++) {
            float rr = 0.f, ii = 0.f;
#pragma unroll
            for (int i = 0; i < W; i++) {
                float wwr = pwr[i * W + o], wwi = pwi[i * W + o];
                rr += ar[i] * wwr - ai[i] * wwi;
                ii += ar[i] * wwi + ai[i] * wwr;
            }
            if (corner) {
                rr += ere[ebase + o * NMODE];
                ii += eim[ebase + o * NMODE];
            }
            rr_[o] = rr * sm;
            ri_[o] = ii * sm;
        }
    }
    // ---- fc1 -> cgelu -> fc2 (real out) ----
    float accr[3] = {0.f, 0.f, 0.f};
    for (int jc = 0; jc < 16; jc++) {
        int jb = jc * 8;
        float tr[8], ti[8];
#pragma unroll
        for (int jj = 0; jj < 8; jj++) { tr[jj] = 0.f; ti[jj] = 0.f; }
#pragma unroll 1
        for (int i = 0; i < W; i++) {
            float4 wrA = *(const float4*)&w1r[i * 128 + jb];
            float4 wrB = *(const float4*)&w1r[i * 128 + jb + 4];
            float4 wiA = *(const float4*)&w1i[i * 128 + jb];
            float4 wiB = *(const float4*)&w1i[i * 128 + jb + 4];
            float xr_ = rr_[i], xi_ = ri_[i];
            tr[0] += xr_ * wrA.x - xi_ * wiA.x;  ti[0] += xr_ * wiA.x + xi_ * wrA.x;
            tr[1] += xr_ * wrA.y - xi_ * wiA.y;  ti[1] += xr_ * wiA.y + xi_ * wrA.y;
            tr[2] += xr_ * wrA.z - xi_ * wiA.z;  ti[2] += xr_ * wiA.z + xi_ * wrA.z;
            tr[3] += xr_ * wrA.w - xi_ * wiA.w;  ti[3] += xr_ * wiA.w + xi_ * wrA.w;
            tr[4] += xr_ * wrB.x - xi_ * wiB.x;  ti[4] += xr_ * wiB.x + xi_ * wrB.x;
            tr[5] += xr_ * wrB.y - xi_ * wiB.y;  ti[5] += xr_ * wiB.y + xi_ * wrB.y;
            tr[6] += xr_ * wrB.z - xi_ * wiB.z;  ti[6] += xr_ * wiB.z + xi_ * wrB.z;
            tr[7] += xr_ * wrB.w - xi_ * wiB.w;  ti[7] += xr_ * wiB.w + xi_ * wrB.w;
        }
#pragma unroll
        for (int jj = 0; jj < 8; jj++) {
            tr[jj] = n22_gelu(tr[jj]);
            ti[jj] = n22_gelu(ti[jj]);
        }
#pragma unroll
        for (int o = 0; o < 3; o++) {
            float4 crA = *(const float4*)&w2r[o * 128 + jb];
            float4 crB = *(const float4*)&w2r[o * 128 + jb + 4];
            float4 ciA = *(const float4*)&w2i[o * 128 + jb];
            float4 ciB = *(const float4*)&w2i[o * 128 + jb + 4];
            accr[o] += tr[0] * crA.x - ti[0] * ciA.x;
            accr[o] += tr[1] * crA.y - ti[1] * ciA.y;
            accr[o] += tr[2] * crA.z - ti[2] * ciA.z;
            accr[o] += tr[3] * crA.w - ti[3] * ciA.w;
            accr[o] += tr[4] * crB.x - ti[4] * ciB.x;
            accr[o] += tr[5] * crB.y - ti[5] * ciB.y;
            accr[o] += tr[6] * crB.z - ti[6] * ciB.z;
            accr[o] += tr[7] * crB.w - ti[7] * ciB.w;
        }
    }
#pragma unroll
    for (int o = 0; o < 3; o++) {
        size_t k = (size_t)(b * 3 + o) * XYZ + p;
        outf[k] = __bfloat162float(__float2bfloat16(accr[o]));
    }
}

extern "C" void kernel_launch(void* const* d_in, const int* in_sizes, int n_in,
                              void* d_out, int out_size, void* d_ws, size_t ws_size,
                              hipStream_t stream) {
    const float* x_r    = (const float*)d_in[0];
    const float* x_i    = (const float*)d_in[1];
    const float* smooth = (const float*)d_in[2];
    const float* wconv  = (const float*)d_in[3];
    const float* wpt_r  = (const float*)d_in[4];
    const float* wpt_i  = (const float*)d_in[5];
    const float* fc0_r  = (const float*)d_in[6];
    const float* fc0_i  = (const float*)d_in[7];
    const float* fc1_r  = (const float*)d_in[8];
    const float* fc1_i  = (const float*)d_in[9];
    const float* fc2_r  = (const float*)d_in[10];
    const float* fc2_i  = (const float*)d_in[11];
    float* outf = (float*)d_out;

    const size_t NBW = (size_t)4 * W * XYZ;
    const size_t NM  = (size_t)80 * NMODE;
    const size_t NR  = (size_t)80 * NREAL;

    float* ws  = (float*)d_ws;
    float* eRe = ws;
    float* eIm = eRe + NM;
    float* tRe = eIm + NM;
    float* tIm = tRe + NM;
    float* r1  = tIm + NM;
    float* r2  = r1 + NR;
    float* xre = r2 + NR;
    float* xim = xre + NBW;

    dim3 blk(256);
    const int gP = (4 * XYZ) / 256;    // 2112
    const int gM = (80 * NMODE) / 256; // 640
    const int gR = (80 * NREAL) / 256; // 1120

    n22_fc0<<<gP, blk, 0, stream>>>(x_r, x_i, fc0_r, fc0_i, xre, xim);
    for (int l = 0; l < 4; l++) {
        n22_ixy<<<640, blk, 0, stream>>>(xre, xim, tRe, tIm);
        n22_irfftz<<<gR, blk, 0, stream>>>(tRe, tIm, r1);
        n22_mix<<<gR, blk, 0, stream>>>(r1, wconv, l, r2);
        n22_rfftz<<<gM, blk, 0, stream>>>(r2, tRe, tIm);
        n22_fxy<<<640, blk, 0, stream>>>(tRe, tIm, eRe, eIm);
        if (l < 3)
            n22_combine<<<gP, blk, 0, stream>>>(xre, xim, eRe, eIm,
                                                wpt_r, wpt_i, l, smooth);
    }
    n22_tail<<<gP, blk, 0, stream>>>(xre, xim, eRe, eIm, wpt_r, wpt_i, smooth,
                                     fc1_r, fc1_i, fc2_r, fc2_i, outf);
}